// Round 6
// baseline (375.965 us; speedup 1.0000x reference)
//
#include <hip/hip_runtime.h>
#include <stdint.h>

#define L_NR 192
#define S_NS 256
#define D_   256
#define H_   8
#define C_   32

typedef __bf16    bf16x8_t __attribute__((ext_vector_type(8)));
typedef _Float16  half4_t  __attribute__((ext_vector_type(4)));
typedef float     f32x4_t  __attribute__((ext_vector_type(4)));

__device__ __forceinline__ float bflo(unsigned int u) { return __uint_as_float(u << 16); }
__device__ __forceinline__ float bfhi(unsigned int u) { return __uint_as_float(u & 0xffff0000u); }
__device__ __forceinline__ unsigned int f2b(float f) {
    unsigned int x = __float_as_uint(f);
    return (x + 0x7fffu + ((x >> 16) & 1u)) >> 16;   // RNE
}
__device__ __forceinline__ unsigned short f2h(float f) {
    union { _Float16 h; unsigned short u; } cv; cv.h = (_Float16)f; return cv.u;
}

// ---- Convert 5 fp32 weight matrices (256x256) to bf16 in workspace ----
__global__ __launch_bounds__(256) void convw_kernel(
    const float* __restrict__ wq, const float* __restrict__ wk,
    const float* __restrict__ wv, const float* __restrict__ wg,
    const float* __restrict__ wo, unsigned short* __restrict__ dst)
{
    int mat = blockIdx.y;
    const float* src = (mat == 0) ? wq : (mat == 1) ? wk : (mat == 2) ? wv
                     : (mat == 3) ? wg : wo;
    int i = (blockIdx.x * 256 + threadIdx.x) * 4;
    float4 v = *(const float4*)(src + i);
    uint2 w;
    w.x = f2b(v.x) | (f2b(v.y) << 16);
    w.y = f2b(v.z) | (f2b(v.w) << 16);
    *(uint2*)(dst + (size_t)mat * 65536 + i) = w;
}

// ---------------- LayerNorm: m fp32 (S,L,D) -> xn bf16 (L,S,D) ----------------
__global__ __launch_bounds__(256) void ln_kernel(
    const float* __restrict__ m,
    const float* __restrict__ lns,
    const float* __restrict__ lnb,
    unsigned short* __restrict__ xn)
{
    int tid = threadIdx.x;
    int lane = tid & 63, wave = tid >> 6;
    int r = blockIdx.x * 4 + wave;          // r = s*L + l
    int s = r / L_NR, l = r % L_NR;

    float4 x = ((const float4*)(m + (size_t)r * D_))[lane];

    float sum = x.x + x.y + x.z + x.w;
    float ss  = x.x*x.x + x.y*x.y + x.z*x.z + x.w*x.w;
#pragma unroll
    for (int off = 32; off > 0; off >>= 1) {
        sum += __shfl_xor(sum, off, 64);
        ss  += __shfl_xor(ss,  off, 64);
    }
    float mean = sum * (1.0f/256.0f);
    float var  = ss  * (1.0f/256.0f) - mean * mean;
    float rstd = rsqrtf(fmaxf(var, 0.0f) + 1e-5f);

    float4 sc = ((const float4*)lns)[lane];
    float4 bi = ((const float4*)lnb)[lane];

    float y0 = (x.x - mean) * rstd * sc.x + bi.x;
    float y1 = (x.y - mean) * rstd * sc.y + bi.y;
    float y2 = (x.z - mean) * rstd * sc.z + bi.z;
    float y3 = (x.w - mean) * rstd * sc.w + bi.w;

    uint2 w;
    w.x = f2b(y0) | (f2b(y1) << 16);
    w.y = f2b(y2) | (f2b(y3) << 16);
    *(uint2*)(xn + ((size_t)l * S_NS + s) * D_ + lane * 4) = w;
}

// ------------- Projections (register-B): xn @ W^T -------------
// grid (192, 32): x = l (256 rows); y: mat = y>>3, h = y&7 (32 cols = 1 head).
// B chunk = 32x256 bf16 = 16 frags/wave in VGPRs; k-loop has NO LDS, NO barrier.
// Epilogue: LDS transpose tile -> contiguous uint4 stores (each mat's (l,h)
// chunk is a contiguous 256x32 region).
#define TLP 40   // LDS transpose tile row stride (elems)

__global__ __launch_bounds__(256) void proj_kernel(
    const unsigned short* __restrict__ xn,
    const unsigned short* __restrict__ wbf,   // 4 matrices, bf16, 65536 each
    const float* __restrict__ bg,
    unsigned short* __restrict__ qb, unsigned short* __restrict__ kb,
    unsigned short* __restrict__ vb, unsigned short* __restrict__ gb)
{
    __shared__ __align__(16) unsigned short Tl[S_NS * TLP];   // 20480 B

    int tid  = threadIdx.x;
    int lane = tid & 63, wave = tid >> 6;
    int quad = lane >> 4, l16 = lane & 15;
    int mat = blockIdx.y >> 3;
    int h   = blockIdx.y & 7;
    int n0  = h * 32;
    const unsigned short* W = wbf + (size_t)mat * 65536 + (size_t)n0 * 256;

    // B fragments -> registers (16 loads, one wait)
    bf16x8_t bfr[8][2];
#pragma unroll
    for (int nt = 0; nt < 2; ++nt) {
        const unsigned short* Wn = W + (size_t)(nt * 16 + l16) * 256 + quad * 8;
#pragma unroll
        for (int ks = 0; ks < 8; ++ks)
            bfr[ks][nt] = *(const bf16x8_t*)(Wn + ks * 32);
    }

    int row0 = blockIdx.x * 256 + wave * 64;
    const unsigned short* arow = xn + (size_t)(row0 + l16) * D_ + quad * 8;

    f32x4_t acc[4][2];
#pragma unroll
    for (int mt = 0; mt < 4; ++mt)
#pragma unroll
        for (int nt = 0; nt < 2; ++nt) acc[mt][nt] = (f32x4_t){0.f,0.f,0.f,0.f};

    bf16x8_t a_cur[4], a_nxt[4];
#pragma unroll
    for (int mt = 0; mt < 4; ++mt) a_cur[mt] = *(const bf16x8_t*)(arow + mt * 16 * D_);

#pragma unroll
    for (int ks = 0; ks < 8; ++ks) {
        if (ks < 7) {
#pragma unroll
            for (int mt = 0; mt < 4; ++mt)
                a_nxt[mt] = *(const bf16x8_t*)(arow + mt * 16 * D_ + (ks + 1) * 32);
        }
#pragma unroll
        for (int nt = 0; nt < 2; ++nt)
#pragma unroll
            for (int mt = 0; mt < 4; ++mt)
                acc[mt][nt] = __builtin_amdgcn_mfma_f32_16x16x32_bf16(a_cur[mt], bfr[ks][nt], acc[mt][nt], 0, 0, 0);
#pragma unroll
        for (int mt = 0; mt < 4; ++mt) a_cur[mt] = a_nxt[mt];
    }

    // epilogue: acc -> LDS tile [s][c] with per-mat pointwise op
    const float qscale = 0.17677669529663687f;  // 1/sqrt(32)
#pragma unroll
    for (int nt = 0; nt < 2; ++nt) {
        int n = n0 + nt * 16 + l16;
        float bgn = bg[n];
#pragma unroll
        for (int mt = 0; mt < 4; ++mt) {
#pragma unroll
            for (int r = 0; r < 4; ++r) {
                int srow = wave * 64 + mt * 16 + quad * 4 + r;
                float v = acc[mt][nt][r];
                unsigned short o;
                if (mat == 0)      o = (unsigned short)f2b(v * qscale);
                else if (mat == 1) o = (unsigned short)f2b(v);
                else if (mat == 2) o = f2h(v);                       // v as f16
                else               o = (unsigned short)f2b(1.0f / (1.0f + __expf(-(v + bgn))));
                Tl[srow * TLP + nt * 16 + l16] = o;
            }
        }
    }
    __syncthreads();

    // coalesced store: (l,h) chunk is contiguous 8192 elems for every mat
    unsigned short* dstb = (mat == 0) ? qb : (mat == 1) ? kb : (mat == 2) ? vb : gb;
    unsigned short* dst = dstb + ((size_t)(blockIdx.x * H_ + h)) * (S_NS * C_);
#pragma unroll
    for (int j = 0; j < 4; ++j) {
        int idx = j * 2048 + tid * 8;
        int s = idx >> 5, c8 = idx & 31;
        *(uint4*)(dst + idx) = *(const uint4*)&Tl[s * TLP + c8];
    }
}

// ------------- MFMA attention per (l,h) -------------
#define KP 40    // K LDS row stride (bf16 elems)
#define VP 264   // V^T LDS row stride (f16 elems)
#define VXOR(c) (((((c) >> 3) & 3)) << 4)   // bank-spread swizzle for V^T staging

__global__ __launch_bounds__(256) void attn_kernel(
    const unsigned short* __restrict__ qb, const unsigned short* __restrict__ kb,
    const unsigned short* __restrict__ vb, const unsigned short* __restrict__ gb,
    const int* __restrict__ seq_pad, const int* __restrict__ res_pad,
    unsigned short* __restrict__ ctxg)
{
    __shared__ __align__(16) unsigned short Klds[S_NS * KP];
    __shared__ __align__(16) unsigned short Vlds[C_ * VP];
    __shared__ unsigned int padm[16];
    __shared__ int flagall;
    __shared__ float invb[64];

    int tid  = threadIdx.x;
    int lane = tid & 63, wave = tid >> 6;
    int quad = lane >> 4, l16 = lane & 15;
    int lh = blockIdx.x, l = lh >> 3, h = lh & 7;
    size_t base = (size_t)lh * (S_NS * C_);

    const uint4* ksrc = (const uint4*)(kb + base);
#pragma unroll
    for (int i = 0; i < 4; ++i) {
        int idx = i * 256 + tid;
        int s = idx >> 2, c8 = (idx & 3) * 8;
        *(uint4*)(Klds + s * KP + c8) = ksrc[idx];
    }
    // stage V (row-major f16 (S,C)) -> transposed V^T LDS [c][s], swizzled
    const uint4* vsrc = (const uint4*)(vb + base);
#pragma unroll
    for (int i = 0; i < 4; ++i) {
        int idx = i * 256 + tid;
        int s = idx >> 2, c8 = (idx & 3) * 8;
        uint4 d = vsrc[idx];
        const unsigned short* p = (const unsigned short*)&d;
#pragma unroll
        for (int k = 0; k < 8; ++k) {
            int c = c8 + k;
            Vlds[c * VP + (s ^ VXOR(c))] = p[k];
        }
    }
    if (tid < 16) {
        unsigned int pm = 0;
        for (int mt = 0; mt < 16; ++mt)
            pm |= (seq_pad[mt * 16 + tid] != 0 ? 1u : 0u) << mt;
        padm[tid] = pm;
    }
    __syncthreads();
    if (tid == 0) {
        unsigned int a = 0xFFFFu;
        for (int i = 0; i < 16; ++i) a &= padm[i];
        flagall = (res_pad[l] != 0) || (a == 0xFFFFu);
    }
    __syncthreads();

    unsigned int keep[4];
#pragma unroll
    for (int r = 0; r < 4; ++r)
        keep[r] = flagall ? 0xFFFFu : (~padm[quad * 4 + r] & 0xFFFFu);

    const float LOG2E = 1.4426950408889634f;
    int vx0 = VXOR(l16), vx1 = VXOR(16 + l16);

    for (int qt = 0; qt < 4; ++qt) {
        int sb = wave * 64 + qt * 16;
        bf16x8_t qf = *(const bf16x8_t*)(qb + base + (size_t)(sb + l16) * C_ + quad * 8);
        f32x4_t acc[16];
#pragma unroll
        for (int kt = 0; kt < 16; ++kt) {
            bf16x8_t kf = *(const bf16x8_t*)(Klds + (kt * 16 + l16) * KP + quad * 8);
            acc[kt] = __builtin_amdgcn_mfma_f32_16x16x32_bf16(kf, qf, (f32x4_t){0.f,0.f,0.f,0.f}, 0, 0, 0);
        }
        float mx = -3.0e38f;
#pragma unroll
        for (int kt = 0; kt < 16; ++kt)
            mx = fmaxf(mx, fmaxf(fmaxf(acc[kt][0], acc[kt][1]), fmaxf(acc[kt][2], acc[kt][3])));
        mx = fmaxf(mx, __shfl_xor(mx, 16, 64));
        mx = fmaxf(mx, __shfl_xor(mx, 32, 64));
        float mk = mx * LOG2E;
        float sumv = 0.0f;
#pragma unroll
        for (int kt = 0; kt < 16; ++kt) {
#pragma unroll
            for (int r = 0; r < 4; ++r) {
                float e = __builtin_amdgcn_exp2f(acc[kt][r] * LOG2E - mk);
                e = ((keep[r] >> kt) & 1u) ? e : 0.0f;
                acc[kt][r] = e;
                sumv += e;
            }
        }
        sumv += __shfl_xor(sumv, 16, 64);
        sumv += __shfl_xor(sumv, 32, 64);
        float inv = 1.0f / sumv;
        if (quad == 0) invb[wave * 16 + l16] = inv;

        half4_t pf[16];
#pragma unroll
        for (int kt = 0; kt < 16; ++kt) {
            half4_t t;
            t[0] = (_Float16)acc[kt][0]; t[1] = (_Float16)acc[kt][1];
            t[2] = (_Float16)acc[kt][2]; t[3] = (_Float16)acc[kt][3];
            pf[kt] = t;
        }
        f32x4_t c0 = (f32x4_t){0.f,0.f,0.f,0.f}, c1 = (f32x4_t){0.f,0.f,0.f,0.f};
#pragma unroll
        for (int kt = 0; kt < 16; ++kt) {
            int toff = kt * 16 + quad * 4;
            half4_t v0 = *(const half4_t*)(Vlds + l16 * VP        + (toff ^ vx0));
            half4_t v1 = *(const half4_t*)(Vlds + (16 + l16) * VP + (toff ^ vx1));
            c0 = __builtin_amdgcn_mfma_f32_16x16x16f16(pf[kt], v0, c0, 0, 0, 0);
            c1 = __builtin_amdgcn_mfma_f32_16x16x16f16(pf[kt], v1, c1, 0, 0, 0);
        }
#pragma unroll
        for (int r = 0; r < 4; ++r) {
            int s = sb + quad * 4 + r;
            float iv = invb[wave * 16 + quad * 4 + r];
            float g0 = bflo((unsigned int)gb[base + (size_t)s * C_ + l16]);
            float g1 = bflo((unsigned int)gb[base + (size_t)s * C_ + 16 + l16]);
            unsigned short* op = ctxg + (size_t)(l * S_NS + s) * D_ + h * C_;
            op[l16]      = (unsigned short)f2b(c0[r] * iv * g0);
            op[16 + l16] = (unsigned short)f2b(c1[r] * iv * g1);
        }
    }
}

// ------------- Output projection (register-B): ctxg @ wo^T + bo -> out fp32 (S,L,D) -------------
// grid (192, 8): x = l, y = 32-col chunk.
__global__ __launch_bounds__(256) void out_kernel(
    const unsigned short* __restrict__ ctxg,
    const unsigned short* __restrict__ wob,   // bf16 wo
    const float* __restrict__ bo,
    float* __restrict__ out)
{
    int tid  = threadIdx.x;
    int lane = tid & 63, wave = tid >> 6;
    int quad = lane >> 4, l16 = lane & 15;
    int n0   = blockIdx.y * 32;
    const unsigned short* W = wob + (size_t)n0 * 256;

    bf16x8_t bfr[8][2];
#pragma unroll
    for (int nt = 0; nt < 2; ++nt) {
        const unsigned short* Wn = W + (size_t)(nt * 16 + l16) * 256 + quad * 8;
#pragma unroll
        for (int ks = 0; ks < 8; ++ks)
            bfr[ks][nt] = *(const bf16x8_t*)(Wn + ks * 32);
    }

    int row0 = blockIdx.x * 256 + wave * 64;
    const unsigned short* arow = ctxg + (size_t)(row0 + l16) * D_ + quad * 8;

    f32x4_t acc[4][2];
#pragma unroll
    for (int mt = 0; mt < 4; ++mt)
#pragma unroll
        for (int nt = 0; nt < 2; ++nt) acc[mt][nt] = (f32x4_t){0.f,0.f,0.f,0.f};

    bf16x8_t a_cur[4], a_nxt[4];
#pragma unroll
    for (int mt = 0; mt < 4; ++mt) a_cur[mt] = *(const bf16x8_t*)(arow + mt * 16 * D_);

#pragma unroll
    for (int ks = 0; ks < 8; ++ks) {
        if (ks < 7) {
#pragma unroll
            for (int mt = 0; mt < 4; ++mt)
                a_nxt[mt] = *(const bf16x8_t*)(arow + mt * 16 * D_ + (ks + 1) * 32);
        }
#pragma unroll
        for (int nt = 0; nt < 2; ++nt)
#pragma unroll
            for (int mt = 0; mt < 4; ++mt)
                acc[mt][nt] = __builtin_amdgcn_mfma_f32_16x16x32_bf16(a_cur[mt], bfr[ks][nt], acc[mt][nt], 0, 0, 0);
#pragma unroll
        for (int mt = 0; mt < 4; ++mt) a_cur[mt] = a_nxt[mt];
    }

    int l = blockIdx.x;
#pragma unroll
    for (int nt = 0; nt < 2; ++nt) {
        int n = n0 + nt * 16 + l16;
        float bias = bo[n];
#pragma unroll
        for (int mt = 0; mt < 4; ++mt) {
#pragma unroll
            for (int r = 0; r < 4; ++r) {
                int s = (wave * 64 + mt * 16 + quad * 4 + r);
                out[((size_t)s * L_NR + l) * D_ + n] = acc[mt][nt][r] + bias;
            }
        }
    }
}

extern "C" void kernel_launch(void* const* d_in, const int* in_sizes, int n_in,
                              void* d_out, int out_size, void* d_ws, size_t ws_size,
                              hipStream_t stream) {
    const float* m     = (const float*)d_in[0];
    const int* seq_pad = (const int*)d_in[1];
    const int* res_pad = (const int*)d_in[2];
    const float* lns   = (const float*)d_in[3];
    const float* lnb   = (const float*)d_in[4];
    const float* wq    = (const float*)d_in[5];
    const float* wk    = (const float*)d_in[6];
    const float* wv    = (const float*)d_in[7];
    const float* wg    = (const float*)d_in[8];
    const float* bg    = (const float*)d_in[9];
    const float* wo    = (const float*)d_in[10];
    const float* bo    = (const float*)d_in[11];
    float* out         = (float*)d_out;

    const size_t NE = (size_t)L_NR * S_NS * D_;   // 12,582,912 elements
    unsigned short* xn = (unsigned short*)d_ws;   // bf16 (L,S,D); reused as ctxg
    unsigned short* qb = xn + NE;
    unsigned short* kb = qb + NE;
    unsigned short* vb = kb + NE;                 // f16 (L,H,S,C) row-major
    unsigned short* gb = vb + NE;
    unsigned short* wbf = gb + NE;                // 5 x 65536 bf16 weights
    unsigned short* ctxg = xn;                    // attn no longer needs xn

    convw_kernel<<<dim3(64, 5), 256, 0, stream>>>(wq, wk, wv, wg, wo, wbf);
    ln_kernel<<<12288, 256, 0, stream>>>(m, lns, lnb, xn);
    proj_kernel<<<dim3(192, 32), 256, 0, stream>>>(xn, wbf, bg, qb, kb, vb, gb);
    attn_kernel<<<L_NR * H_, 256, 0, stream>>>(qb, kb, vb, gb, seq_pad, res_pad, ctxg);
    out_kernel<<<dim3(192, 8), 256, 0, stream>>>(ctxg, wbf + 4 * 65536, bo, out);
}

// Round 7
// 290.825 us; speedup vs baseline: 1.2928x; 1.2928x over previous
//
#include <hip/hip_runtime.h>
#include <stdint.h>

#define L_NR 192
#define S_NS 256
#define D_   256
#define H_   8
#define C_   32

typedef __bf16    bf16x8_t __attribute__((ext_vector_type(8)));
typedef _Float16  half4_t  __attribute__((ext_vector_type(4)));
typedef float     f32x4_t  __attribute__((ext_vector_type(4)));

__device__ __forceinline__ float bflo(unsigned int u) { return __uint_as_float(u << 16); }
__device__ __forceinline__ float bfhi(unsigned int u) { return __uint_as_float(u & 0xffff0000u); }
__device__ __forceinline__ unsigned int f2b(float f) {
    unsigned int x = __float_as_uint(f);
    return (x + 0x7fffu + ((x >> 16) & 1u)) >> 16;   // RNE
}
__device__ __forceinline__ unsigned short f2h(float f) {
    union { _Float16 h; unsigned short u; } cv; cv.h = (_Float16)f; return cv.u;
}

// ---- Convert 5 fp32 weight matrices (256x256) to bf16 in workspace ----
__global__ __launch_bounds__(256) void convw_kernel(
    const float* __restrict__ wq, const float* __restrict__ wk,
    const float* __restrict__ wv, const float* __restrict__ wg,
    const float* __restrict__ wo, unsigned short* __restrict__ dst)
{
    int mat = blockIdx.y;
    const float* src = (mat == 0) ? wq : (mat == 1) ? wk : (mat == 2) ? wv
                     : (mat == 3) ? wg : wo;
    int i = (blockIdx.x * 256 + threadIdx.x) * 4;
    float4 v = *(const float4*)(src + i);
    uint2 w;
    w.x = f2b(v.x) | (f2b(v.y) << 16);
    w.y = f2b(v.z) | (f2b(v.w) << 16);
    *(uint2*)(dst + (size_t)mat * 65536 + i) = w;
}

// ---------------- LayerNorm: m fp32 (S,L,D) -> xn bf16 (L,S,D) ----------------
__global__ __launch_bounds__(256) void ln_kernel(
    const float* __restrict__ m,
    const float* __restrict__ lns,
    const float* __restrict__ lnb,
    unsigned short* __restrict__ xn)
{
    int tid = threadIdx.x;
    int lane = tid & 63, wave = tid >> 6;
    int r = blockIdx.x * 4 + wave;          // r = s*L + l
    int s = r / L_NR, l = r % L_NR;

    float4 x = ((const float4*)(m + (size_t)r * D_))[lane];

    float sum = x.x + x.y + x.z + x.w;
    float ss  = x.x*x.x + x.y*x.y + x.z*x.z + x.w*x.w;
#pragma unroll
    for (int off = 32; off > 0; off >>= 1) {
        sum += __shfl_xor(sum, off, 64);
        ss  += __shfl_xor(ss,  off, 64);
    }
    float mean = sum * (1.0f/256.0f);
    float var  = ss  * (1.0f/256.0f) - mean * mean;
    float rstd = rsqrtf(fmaxf(var, 0.0f) + 1e-5f);

    float4 sc = ((const float4*)lns)[lane];
    float4 bi = ((const float4*)lnb)[lane];

    float y0 = (x.x - mean) * rstd * sc.x + bi.x;
    float y1 = (x.y - mean) * rstd * sc.y + bi.y;
    float y2 = (x.z - mean) * rstd * sc.z + bi.z;
    float y3 = (x.w - mean) * rstd * sc.w + bi.w;

    uint2 w;
    w.x = f2b(y0) | (f2b(y1) << 16);
    w.y = f2b(y2) | (f2b(y3) << 16);
    *(uint2*)(xn + ((size_t)l * S_NS + s) * D_ + lane * 4) = w;
}

// ------------- Projections (LDS-B, conflict-free swizzle): xn @ W^T -------------
// grid (192, 16): x = l (256 rows); y: mat = y>>2, 64-col chunk = (y&3)*64.
// B LDS layout: elem = ks*2048 + nt*512 + kq*128 + (n8 ^ kq ^ ((ks&1)<<2))*8 + j
//   staging writes: 8 accesses/bank per instr (ideal); ds_read_b128: ideal too.
// Epilogue: same LDS reused as a 256x64 transpose tile (stride 72) -> uint4 stores.
#define TP 72

__global__ __launch_bounds__(256) void proj_kernel(
    const unsigned short* __restrict__ xn,
    const unsigned short* __restrict__ wbf,   // 4 matrices, bf16, 65536 each
    const float* __restrict__ bg,
    unsigned short* __restrict__ qb, unsigned short* __restrict__ kb,
    unsigned short* __restrict__ vb, unsigned short* __restrict__ gb)
{
    __shared__ __align__(16) unsigned short Sl[S_NS * TP];   // 36864 B (B-stage: first 32 KB)

    int tid  = threadIdx.x;
    int lane = tid & 63, wave = tid >> 6;
    int quad = lane >> 4, l16 = lane & 15;
    int mat = blockIdx.y >> 2;
    int n0  = (blockIdx.y & 3) * 64;
    int l   = blockIdx.x;
    const unsigned short* W = wbf + (size_t)mat * 65536 + (size_t)n0 * 256;

    // stage B chunk (64 n x 256 k): coalesced global, swizzled LDS
#pragma unroll
    for (int j = 0; j < 8; ++j) {
        int c  = j * 256 + tid;
        int n  = c >> 5, kk = c & 31;
        int ks = kk >> 2, kq = kk & 3;
        int sw = (n & 15) ^ kq ^ ((ks & 1) << 2);
        uint4 d = *(const uint4*)(W + n * 256 + kk * 8);
        *(uint4*)&Sl[ks * 2048 + (n >> 4) * 512 + kq * 128 + sw * 8] = d;
    }
    __syncthreads();

    int row0 = l * 256 + wave * 64;
    const unsigned short* arow = xn + (size_t)(row0 + l16) * D_ + quad * 8;

    f32x4_t acc[4][4];
#pragma unroll
    for (int mt = 0; mt < 4; ++mt)
#pragma unroll
        for (int nt = 0; nt < 4; ++nt) acc[mt][nt] = (f32x4_t){0.f,0.f,0.f,0.f};

    bf16x8_t a_cur[4], a_nxt[4];
#pragma unroll
    for (int mt = 0; mt < 4; ++mt) a_cur[mt] = *(const bf16x8_t*)(arow + mt * 16 * D_);

    int swb = l16 ^ quad;
#pragma unroll
    for (int ks = 0; ks < 8; ++ks) {
        if (ks < 7) {
#pragma unroll
            for (int mt = 0; mt < 4; ++mt)
                a_nxt[mt] = *(const bf16x8_t*)(arow + mt * 16 * D_ + (ks + 1) * 32);
        }
        int kbase = ks * 2048 + quad * 128 + (swb ^ ((ks & 1) << 2)) * 8;
#pragma unroll
        for (int nt = 0; nt < 4; ++nt) {
            bf16x8_t bfr = *(const bf16x8_t*)&Sl[kbase + nt * 512];
#pragma unroll
            for (int mt = 0; mt < 4; ++mt)
                acc[mt][nt] = __builtin_amdgcn_mfma_f32_16x16x32_bf16(a_cur[mt], bfr, acc[mt][nt], 0, 0, 0);
        }
#pragma unroll
        for (int mt = 0; mt < 4; ++mt) a_cur[mt] = a_nxt[mt];
    }
    __syncthreads();   // B-stage dead; Sl becomes the transpose tile

    const float qscale = 0.17677669529663687f;  // 1/sqrt(32)
#pragma unroll
    for (int nt = 0; nt < 4; ++nt) {
        int n = n0 + nt * 16 + l16;
        float bgn = bg[n];
#pragma unroll
        for (int mt = 0; mt < 4; ++mt) {
#pragma unroll
            for (int r = 0; r < 4; ++r) {
                int srow = wave * 64 + mt * 16 + quad * 4 + r;
                float v = acc[mt][nt][r];
                unsigned short o;
                if (mat == 0)      o = (unsigned short)f2b(v * qscale);
                else if (mat == 1) o = (unsigned short)f2b(v);
                else if (mat == 2) o = f2h(v);                       // v as f16
                else               o = (unsigned short)f2b(1.0f / (1.0f + __expf(-(v + bgn))));
                Sl[srow * TP + nt * 16 + l16] = o;
            }
        }
    }
    __syncthreads();

    // coalesced store: chunk = heads h0,h0+1 contiguous (each 8192 elems)
    unsigned short* dstb = (mat == 0) ? qb : (mat == 1) ? kb : (mat == 2) ? vb : gb;
    size_t cbase = ((size_t)l * H_ + (n0 >> 5)) * 8192;
#pragma unroll
    for (int j = 0; j < 8; ++j) {
        int idx = j * 2048 + tid * 8;       // 16384 elems total
        int s = idx >> 6, c8 = idx & 63;
        uint4 d = *(const uint4*)&Sl[s * TP + c8];
        *(uint4*)(dstb + cbase + (size_t)(c8 >> 5) * 8192 + s * 32 + (c8 & 31)) = d;
    }
}

// ------------- MFMA attention per (l,h) -------------
#define KP 40    // K LDS row stride (bf16 elems)
#define VP 264   // V^T LDS row stride (f16 elems)
#define VXOR(c) (((((c) >> 3) & 3)) << 4)   // bank-spread swizzle for V^T staging

__global__ __launch_bounds__(256) void attn_kernel(
    const unsigned short* __restrict__ qb, const unsigned short* __restrict__ kb,
    const unsigned short* __restrict__ vb, const unsigned short* __restrict__ gb,
    const int* __restrict__ seq_pad, const int* __restrict__ res_pad,
    unsigned short* __restrict__ ctxg)
{
    __shared__ __align__(16) unsigned short Klds[S_NS * KP];
    __shared__ __align__(16) unsigned short Vlds[C_ * VP];
    __shared__ unsigned int padm[16];
    __shared__ int flagall;
    __shared__ float invb[64];

    int tid  = threadIdx.x;
    int lane = tid & 63, wave = tid >> 6;
    int quad = lane >> 4, l16 = lane & 15;
    int lh = blockIdx.x, l = lh >> 3, h = lh & 7;
    size_t base = (size_t)lh * (S_NS * C_);

    const uint4* ksrc = (const uint4*)(kb + base);
#pragma unroll
    for (int i = 0; i < 4; ++i) {
        int idx = i * 256 + tid;
        int s = idx >> 2, c8 = (idx & 3) * 8;
        *(uint4*)(Klds + s * KP + c8) = ksrc[idx];
    }
    // stage V (row-major f16 (S,C)) -> transposed V^T LDS [c][s], swizzled
    const uint4* vsrc = (const uint4*)(vb + base);
#pragma unroll
    for (int i = 0; i < 4; ++i) {
        int idx = i * 256 + tid;
        int s = idx >> 2, c8 = (idx & 3) * 8;
        uint4 d = vsrc[idx];
        const unsigned short* p = (const unsigned short*)&d;
#pragma unroll
        for (int k = 0; k < 8; ++k) {
            int c = c8 + k;
            Vlds[c * VP + (s ^ VXOR(c))] = p[k];
        }
    }
    if (tid < 16) {
        unsigned int pm = 0;
        for (int mt = 0; mt < 16; ++mt)
            pm |= (seq_pad[mt * 16 + tid] != 0 ? 1u : 0u) << mt;
        padm[tid] = pm;
    }
    __syncthreads();
    if (tid == 0) {
        unsigned int a = 0xFFFFu;
        for (int i = 0; i < 16; ++i) a &= padm[i];
        flagall = (res_pad[l] != 0) || (a == 0xFFFFu);
    }
    __syncthreads();

    unsigned int keep[4];
#pragma unroll
    for (int r = 0; r < 4; ++r)
        keep[r] = flagall ? 0xFFFFu : (~padm[quad * 4 + r] & 0xFFFFu);

    const float LOG2E = 1.4426950408889634f;
    int vx0 = VXOR(l16), vx1 = VXOR(16 + l16);

    for (int qt = 0; qt < 4; ++qt) {
        int sb = wave * 64 + qt * 16;
        bf16x8_t qf = *(const bf16x8_t*)(qb + base + (size_t)(sb + l16) * C_ + quad * 8);
        f32x4_t acc[16];
#pragma unroll
        for (int kt = 0; kt < 16; ++kt) {
            bf16x8_t kf = *(const bf16x8_t*)(Klds + (kt * 16 + l16) * KP + quad * 8);
            acc[kt] = __builtin_amdgcn_mfma_f32_16x16x32_bf16(kf, qf, (f32x4_t){0.f,0.f,0.f,0.f}, 0, 0, 0);
        }
        float mx = -3.0e38f;
#pragma unroll
        for (int kt = 0; kt < 16; ++kt)
            mx = fmaxf(mx, fmaxf(fmaxf(acc[kt][0], acc[kt][1]), fmaxf(acc[kt][2], acc[kt][3])));
        mx = fmaxf(mx, __shfl_xor(mx, 16, 64));
        mx = fmaxf(mx, __shfl_xor(mx, 32, 64));
        float mk = mx * LOG2E;
        float sumv = 0.0f;
#pragma unroll
        for (int kt = 0; kt < 16; ++kt) {
#pragma unroll
            for (int r = 0; r < 4; ++r) {
                float e = __builtin_amdgcn_exp2f(acc[kt][r] * LOG2E - mk);
                e = ((keep[r] >> kt) & 1u) ? e : 0.0f;
                acc[kt][r] = e;
                sumv += e;
            }
        }
        sumv += __shfl_xor(sumv, 16, 64);
        sumv += __shfl_xor(sumv, 32, 64);
        float inv = 1.0f / sumv;
        if (quad == 0) invb[wave * 16 + l16] = inv;

        half4_t pf[16];
#pragma unroll
        for (int kt = 0; kt < 16; ++kt) {
            half4_t t;
            t[0] = (_Float16)acc[kt][0]; t[1] = (_Float16)acc[kt][1];
            t[2] = (_Float16)acc[kt][2]; t[3] = (_Float16)acc[kt][3];
            pf[kt] = t;
        }
        f32x4_t c0 = (f32x4_t){0.f,0.f,0.f,0.f}, c1 = (f32x4_t){0.f,0.f,0.f,0.f};
#pragma unroll
        for (int kt = 0; kt < 16; ++kt) {
            int toff = kt * 16 + quad * 4;
            half4_t v0 = *(const half4_t*)(Vlds + l16 * VP        + (toff ^ vx0));
            half4_t v1 = *(const half4_t*)(Vlds + (16 + l16) * VP + (toff ^ vx1));
            c0 = __builtin_amdgcn_mfma_f32_16x16x16f16(pf[kt], v0, c0, 0, 0, 0);
            c1 = __builtin_amdgcn_mfma_f32_16x16x16f16(pf[kt], v1, c1, 0, 0, 0);
        }
#pragma unroll
        for (int r = 0; r < 4; ++r) {
            int s = sb + quad * 4 + r;
            float iv = invb[wave * 16 + quad * 4 + r];
            float g0 = bflo((unsigned int)gb[base + (size_t)s * C_ + l16]);
            float g1 = bflo((unsigned int)gb[base + (size_t)s * C_ + 16 + l16]);
            unsigned short* op = ctxg + (size_t)(l * S_NS + s) * D_ + h * C_;
            op[l16]      = (unsigned short)f2b(c0[r] * iv * g0);
            op[16 + l16] = (unsigned short)f2b(c1[r] * iv * g1);
        }
    }
}

// ------------- Output projection (LDS-B): ctxg @ wo^T + bo -> out fp32 (S,L,D) -------------
// grid (192, 4): x = l, y = 64-col chunk.
__global__ __launch_bounds__(256) void out_kernel(
    const unsigned short* __restrict__ ctxg,
    const unsigned short* __restrict__ wob,   // bf16 wo
    const float* __restrict__ bo,
    float* __restrict__ out)
{
    __shared__ __align__(16) unsigned short Bl[16384];   // 32 KB

    int tid  = threadIdx.x;
    int lane = tid & 63, wave = tid >> 6;
    int quad = lane >> 4, l16 = lane & 15;
    int n0   = blockIdx.y * 64;
    int l    = blockIdx.x;
    const unsigned short* W = wob + (size_t)n0 * 256;

#pragma unroll
    for (int j = 0; j < 8; ++j) {
        int c  = j * 256 + tid;
        int n  = c >> 5, kk = c & 31;
        int ks = kk >> 2, kq = kk & 3;
        int sw = (n & 15) ^ kq ^ ((ks & 1) << 2);
        uint4 d = *(const uint4*)(W + n * 256 + kk * 8);
        *(uint4*)&Bl[ks * 2048 + (n >> 4) * 512 + kq * 128 + sw * 8] = d;
    }
    __syncthreads();

    int row0 = l * 256 + wave * 64;
    const unsigned short* arow = ctxg + (size_t)(row0 + l16) * D_ + quad * 8;

    f32x4_t acc[4][4];
#pragma unroll
    for (int mt = 0; mt < 4; ++mt)
#pragma unroll
        for (int nt = 0; nt < 4; ++nt) acc[mt][nt] = (f32x4_t){0.f,0.f,0.f,0.f};

    bf16x8_t a_cur[4], a_nxt[4];
#pragma unroll
    for (int mt = 0; mt < 4; ++mt) a_cur[mt] = *(const bf16x8_t*)(arow + mt * 16 * D_);

    int swb = l16 ^ quad;
#pragma unroll
    for (int ks = 0; ks < 8; ++ks) {
        if (ks < 7) {
#pragma unroll
            for (int mt = 0; mt < 4; ++mt)
                a_nxt[mt] = *(const bf16x8_t*)(arow + mt * 16 * D_ + (ks + 1) * 32);
        }
        int kbase = ks * 2048 + quad * 128 + (swb ^ ((ks & 1) << 2)) * 8;
#pragma unroll
        for (int nt = 0; nt < 4; ++nt) {
            bf16x8_t bfr = *(const bf16x8_t*)&Bl[kbase + nt * 512];
#pragma unroll
            for (int mt = 0; mt < 4; ++mt)
                acc[mt][nt] = __builtin_amdgcn_mfma_f32_16x16x32_bf16(a_cur[mt], bfr, acc[mt][nt], 0, 0, 0);
        }
#pragma unroll
        for (int mt = 0; mt < 4; ++mt) a_cur[mt] = a_nxt[mt];
    }

#pragma unroll
    for (int nt = 0; nt < 4; ++nt) {
        int n = n0 + nt * 16 + l16;
        float bias = bo[n];
#pragma unroll
        for (int mt = 0; mt < 4; ++mt) {
#pragma unroll
            for (int r = 0; r < 4; ++r) {
                int s = wave * 64 + mt * 16 + quad * 4 + r;
                out[((size_t)s * L_NR + l) * D_ + n] = acc[mt][nt][r] + bias;
            }
        }
    }
}

extern "C" void kernel_launch(void* const* d_in, const int* in_sizes, int n_in,
                              void* d_out, int out_size, void* d_ws, size_t ws_size,
                              hipStream_t stream) {
    const float* m     = (const float*)d_in[0];
    const int* seq_pad = (const int*)d_in[1];
    const int* res_pad = (const int*)d_in[2];
    const float* lns   = (const float*)d_in[3];
    const float* lnb   = (const float*)d_in[4];
    const float* wq    = (const float*)d_in[5];
    const float* wk    = (const float*)d_in[6];
    const float* wv    = (const float*)d_in[7];
    const float* wg    = (const float*)d_in[8];
    const float* bg    = (const float*)d_in[9];
    const float* wo    = (const float*)d_in[10];
    const float* bo    = (const float*)d_in[11];
    float* out         = (float*)d_out;

    const size_t NE = (size_t)L_NR * S_NS * D_;   // 12,582,912 elements
    unsigned short* xn = (unsigned short*)d_ws;   // bf16 (L,S,D); reused as ctxg
    unsigned short* qb = xn + NE;
    unsigned short* kb = qb + NE;
    unsigned short* vb = kb + NE;                 // f16 (L,H,S,C) row-major
    unsigned short* gb = vb + NE;
    unsigned short* wbf = gb + NE;                // 5 x 65536 bf16 weights
    unsigned short* ctxg = xn;                    // attn no longer needs xn

    convw_kernel<<<dim3(64, 5), 256, 0, stream>>>(wq, wk, wv, wg, wo, wbf);
    ln_kernel<<<12288, 256, 0, stream>>>(m, lns, lnb, xn);
    proj_kernel<<<dim3(192, 16), 256, 0, stream>>>(xn, wbf, bg, qb, kb, vb, gb);
    attn_kernel<<<L_NR * H_, 256, 0, stream>>>(qb, kb, vb, gb, seq_pad, res_pad, ctxg);
    out_kernel<<<dim3(192, 4), 256, 0, stream>>>(ctxg, wbf + 4 * 65536, bo, out);
}